// Round 17
// baseline (84.317 us; speedup 1.0000x reference)
//
#include <hip/hip_runtime.h>
#include <math.h>

// Problem constants (match reference file)
#define NN   8192   // nodes
#define DF   64     // feature dim
#define KK   16     // k samples
#define MAXNBR 33   // self + up to 32 neighbors (row has <= 32 ones)
#define NT   256    // threads per block (4 waves)
#define NBINS 2048  // histogram bins = top 11 bits of flipped-float key
#define MAXC 544
#define NR   9      // fixed phase-D trip count: c0 = 4g + 64r < 528 for all g
// transposed layout: thread t sums bins 8t..8t+7 conflict-free
#define HIDX(b) ((((b) & 7) << 8) | ((b) >> 3))

typedef unsigned uvec4 __attribute__((ext_vector_type(4)));  // NT-load-compatible

__device__ __forceinline__ unsigned long long kmax(unsigned long long a, unsigned long long b) {
    return a > b ? a : b;
}
__device__ __forceinline__ unsigned long long kmin(unsigned long long a, unsigned long long b) {
    return a > b ? b : a;
}

// 16-lane (DPP-row) tree sum via row_ror adds — VALU pipe only, no DS traffic.
// Pairing/order is bit-identical to the xor{8,4,2,1} shuffle tree (R11-passing).
// After this, ALL 16 lanes of the row hold the full sum.
__device__ __forceinline__ float row_reduce16(float acc) {
    acc += __uint_as_float(__builtin_amdgcn_update_dpp(
        0, (int)__float_as_uint(acc), 0x128, 0xF, 0xF, true));   // row_ror:8
    acc += __uint_as_float(__builtin_amdgcn_update_dpp(
        0, (int)__float_as_uint(acc), 0x124, 0xF, 0xF, true));   // row_ror:4
    acc += __uint_as_float(__builtin_amdgcn_update_dpp(
        0, (int)__float_as_uint(acc), 0x122, 0xF, 0xF, true));   // row_ror:2
    acc += __uint_as_float(__builtin_amdgcn_update_dpp(
        0, (int)__float_as_uint(acc), 0x121, 0xF, 0xF, true));   // row_ror:1
    return acc;
}

// full 64-lane bitonic sort, descending (validated R7/R8/R10/R11)
__device__ __forceinline__ void sort64_desc(unsigned long long& kv, int lane) {
    #pragma unroll
    for (int k = 2; k <= 64; k <<= 1) {
        #pragma unroll
        for (int j = k >> 1; j > 0; j >>= 1) {
            unsigned long long o = __shfl_xor(kv, j);
            bool tmax = (((lane & j) == 0) != ((lane & k) != 0));
            kv = tmax ? kmax(kv, o) : kmin(kv, o);
        }
    }
}

// ---- one block (4 waves) per node ----
__global__ __launch_bounds__(NT, 6)   // 6 blocks/CU: VGPR cap ~85 for the D-pipeline
void fused_kernel(const float* __restrict__ x,
                  const uvec4* __restrict__ adj4,
                  const int*   __restrict__ cs,
                  int*         __restrict__ out)
{
    const int i    = blockIdx.x;           // node id
    const int t    = threadIdx.x;
    const int w    = t >> 6;
    const int lane = t & 63;

    __shared__ unsigned mask[NN / 32];                  // 1 KB dedup bitmap
    __shared__ int nbrs[MAXNBR];
    __shared__ int nnbr;
    __shared__ alignas(16) int cand[MAXC];              // unique candidate values
    __shared__ int ncand;
    __shared__ unsigned long long histsurv[NBINS / 2];  // 8 KB: hist (u32x2048) then surv (u64x544)
    __shared__ unsigned sum256[NT];                     // stage-1 partial sums
    __shared__ int nsurv;
    __shared__ int B_sh;
    unsigned* const hist = reinterpret_cast<unsigned*>(histsurv);
    unsigned long long* const surv = histsurv;

    // ---- phase A: init (cand zero-filled: safe prefetch addresses past ncv) ----
    if (t < NN / 32) mask[t] = 0u;                      // 256 words
    #pragma unroll
    for (int r = 0; r < 4; ++r) histsurv[t + NT * r] = 0ULL;  // clears 2048 u32 bins
    cand[t] = 0; cand[t + NT] = 0;
    if (t < MAXC - 2 * NT) cand[t + 2 * NT] = 0;
    if (t == 0) { nbrs[0] = i; nnbr = 1; ncand = 0; nsurv = 0; }
    __syncthreads();                                    // barrier 1

    // ---- phase B: scan row i — 2048 uint4s, 8/thread, NON-TEMPORAL ----
    const uvec4* __restrict__ row4 = adj4 + (size_t)i * (NN / 4);
    uvec4 v[8];
    #pragma unroll
    for (int u = 0; u < 8; ++u) v[u] = __builtin_nontemporal_load(&row4[t + NT * u]);
    #pragma unroll
    for (int u = 0; u < 8; ++u) {
        if ((v[u].x | v[u].y | v[u].z | v[u].w) != 0u) {    // 1.0f == 0x3F800000
            const int base = 4 * (t + NT * u);
            const unsigned e[4] = {v[u].x, v[u].y, v[u].z, v[u].w};
            #pragma unroll
            for (int c2 = 0; c2 < 4; ++c2) {
                if (e[c2] != 0u) {
                    int s = atomicAdd(&nnbr, 1);
                    if (s < MAXNBR) nbrs[s] = base + c2;
                }
            }
        }
    }
    __syncthreads();                                    // barrier 2

    const int M = min(nnbr, MAXNBR);
    const int total = M * KK;                           // <= 528

    // ---- phase C: gather cs, dedup via bitmap, append uniques to cand list ----
    #pragma unroll
    for (int r = 0; r < 2; ++r) {
        int q = t + NT * r;
        if (q < total) {
            int vv = cs[(size_t)nbrs[q >> 4] * KK + (q & 15)];
            unsigned bit = 1u << (vv & 31);
            unsigned old = atomicOr(&mask[vv >> 5], bit);
            if (!(old & bit)) { int s = atomicAdd(&ncand, 1); cand[s] = vv; }
        }
    }
    const int q2 = 2 * NT + (t - 64);                   // 512..527 for t=64..79
    if (t >= 64 && t < 80 && q2 < total) {
        int vv = cs[(size_t)nbrs[q2 >> 4] * KK + (q2 & 15)];
        unsigned bit = 1u << (vv & 31);
        unsigned old = atomicOr(&mask[vv >> 5], bit);
        if (!(old & bit)) { int s = atomicAdd(&ncand, 1); cand[s] = vv; }
    }
    __syncthreads();                                    // barrier 3

    const int ncv = ncand;                              // unique count

    // ---- phase D: sims — 16-lane groups, 4 cands per int4 LDS read, DPP reduce,
    //      1-deep SOFTWARE PIPELINE: iter r+1's loads issued before iter r's compute ----
    const int g  = t >> 4;                              // 16 groups
    const int gl = t & 15;                              // lane in group
    const float4 xi4 = reinterpret_cast<const float4*>(x + (size_t)i * DF)[gl];
    unsigned long long rkeys[NR];                       // statically indexed
    int4   c4c;
    float4 xv0c, xv1c, xv2c, xv3c;
    {
        const int c0 = 4 * g;
        if (c0 < ncv) {
            c4c  = *reinterpret_cast<const int4*>(&cand[c0]);   // ds_read_b128
            xv0c = reinterpret_cast<const float4*>(x + (size_t)c4c.x * DF)[gl];
            xv1c = reinterpret_cast<const float4*>(x + (size_t)c4c.y * DF)[gl];
            xv2c = reinterpret_cast<const float4*>(x + (size_t)c4c.z * DF)[gl];
            xv3c = reinterpret_cast<const float4*>(x + (size_t)c4c.w * DF)[gl];
        }
    }
    #pragma unroll
    for (int r = 0; r < NR; ++r) {
        const int c0  = 4 * g + 64 * r;
        const int c0n = c0 + 64;
        // prefetch next iteration (independent of this iteration's compute)
        int4   c4n;
        float4 xv0n, xv1n, xv2n, xv3n;
        const bool okn = (r + 1 < NR) && (c0n < ncv);
        if (okn) {
            c4n  = *reinterpret_cast<const int4*>(&cand[c0n]);  // ds_read_b128
            xv0n = reinterpret_cast<const float4*>(x + (size_t)c4n.x * DF)[gl];
            xv1n = reinterpret_cast<const float4*>(x + (size_t)c4n.y * DF)[gl];
            xv2n = reinterpret_cast<const float4*>(x + (size_t)c4n.z * DF)[gl];
            xv3n = reinterpret_cast<const float4*>(x + (size_t)c4n.w * DF)[gl];
        }
        // compute current iteration (loads were issued one iteration ago)
        unsigned long long key = 0ULL;
        if (c0 < ncv) {
            float a0 = 0.f, a1 = 0.f, a2 = 0.f, a3 = 0.f;
            a0 = fmaf(xi4.x, xv0c.x, a0); a0 = fmaf(xi4.y, xv0c.y, a0);
            a0 = fmaf(xi4.z, xv0c.z, a0); a0 = fmaf(xi4.w, xv0c.w, a0);
            a1 = fmaf(xi4.x, xv1c.x, a1); a1 = fmaf(xi4.y, xv1c.y, a1);
            a1 = fmaf(xi4.z, xv1c.z, a1); a1 = fmaf(xi4.w, xv1c.w, a1);
            a2 = fmaf(xi4.x, xv2c.x, a2); a2 = fmaf(xi4.y, xv2c.y, a2);
            a2 = fmaf(xi4.z, xv2c.z, a2); a2 = fmaf(xi4.w, xv2c.w, a2);
            a3 = fmaf(xi4.x, xv3c.x, a3); a3 = fmaf(xi4.y, xv3c.y, a3);
            a3 = fmaf(xi4.z, xv3c.z, a3); a3 = fmaf(xi4.w, xv3c.w, a3);
            a0 = row_reduce16(a0);                      // all 16 lanes get the sum
            a1 = row_reduce16(a1);
            a2 = row_reduce16(a2);
            a3 = row_reduce16(a3);
            // lane gl (< 4) owns candidate c0+gl: one key per lane, in registers
            if (gl < 4 && c0 + gl < ncv) {
                float av = (gl == 0) ? a0 : (gl == 1) ? a1 : (gl == 2) ? a2 : a3;
                int  vb = (gl == 0) ? c4c.x : (gl == 1) ? c4c.y : (gl == 2) ? c4c.z : c4c.w;
                unsigned fb = __float_as_uint(av);
                fb = (fb & 0x80000000u) ? ~fb : (fb | 0x80000000u);  // order-preserving
                key = ((unsigned long long)fb << 13) |
                      (unsigned long long)(unsigned)(8191 - vb);
                atomicAdd(&hist[HIDX((unsigned)(key >> 34))], 1u);   // 16 lanes, 1 instr
            }
        }
        rkeys[r] = key;                                 // 0 = invalid (unreachable code)
        // rotate pipeline registers (pure renaming after full unroll)
        c4c = c4n; xv0c = xv0n; xv1c = xv1n; xv2c = xv2n; xv3c = xv3n;
    }
    __syncthreads();                                    // barrier 4

    if (ncv >= KK) {
        // ---- phase F: find bin B containing the 16th-largest key ----
        unsigned s8 = 0;
        #pragma unroll
        for (int j = 0; j < 8; ++j) s8 += hist[(j << 8) | t];   // bins 8t..8t+7
        sum256[t] = s8;
        __syncthreads();                                // barrier 5
        if (w == 0) {
            // stage 2: 64 chunks of 32 bins, scanned from top
            const int c = 63 - lane;
            unsigned c32 = 0;
            #pragma unroll
            for (int j = 0; j < 4; ++j) c32 += sum256[4 * c + j];
            unsigned p = c32;
            #pragma unroll
            for (int off = 1; off < 64; off <<= 1) {
                unsigned o = __shfl_up(p, off);
                if (lane >= off) p += o;
            }
            unsigned long long bal = __ballot(p >= (unsigned)KK);
            int l1 = (int)__ffsll((unsigned long long)bal) - 1;
            unsigned above1 = __shfl(p - c32, l1);
            int C = 63 - l1;
            // stage 3: 32 bins of chunk C, descending
            int b = 32 * C + 31 - lane;
            unsigned hb = (lane < 32) ? hist[HIDX(b)] : 0u;
            unsigned p2 = hb;
            #pragma unroll
            for (int off = 1; off < 64; off <<= 1) {
                unsigned o = __shfl_up(p2, off);
                if (lane >= off) p2 += o;
            }
            unsigned long long bal2 = __ballot(above1 + p2 >= (unsigned)KK);
            int l2 = (int)__ffsll((unsigned long long)bal2) - 1;
            if (lane == 0) B_sh = 32 * C + 31 - l2;
        }
        __syncthreads();                                // barrier 6 (hist now dead)
        const unsigned Bv = (unsigned)B_sh;

        // ---- phase G: append survivors from REGISTERS; surv aliases dead hist ----
        #pragma unroll
        for (int r = 0; r < NR; ++r) {
            unsigned long long k = rkeys[r];
            if (k != 0ULL && (unsigned)(k >> 34) >= Bv) {
                int s = atomicAdd(&nsurv, 1);
                surv[s] = k;
            }
        }
        __syncthreads();                                // barrier 7

        // ---- phase H: wave 0 sorts survivors exactly (u64 keys) ----
        if (w == 0) {
            const int S = nsurv;                        // >= 16 by construction
            unsigned long long kk = (lane < S) ? surv[lane] : 0ULL;
            sort64_desc(kk, lane);
            int processed = 64;
            while (processed < S) {                     // rare fallback: chunked resort
                if (lane >= 16) {
                    int idx = processed + (lane - 16);
                    kk = (idx < S) ? surv[idx] : 0ULL;
                }
                sort64_desc(kk, lane);
                processed += 48;
            }
            if (lane < KK)
                out[(size_t)i * KK + lane] = 8191 - (int)(kk & 0x1FFFULL);
        }
    } else {
        // rare: fewer than K uniques -> sorted uniques + pad with own samples
        if (t == 0) {
            int sorted_u[KK];
            int cnt2 = 0;
            for (int mw = 0; mw < NN / 32 && cnt2 < KK; ++mw) {
                unsigned b = mask[mw];
                while (b && cnt2 < KK) {
                    int bit = __ffs(b) - 1;
                    b &= b - 1;
                    sorted_u[cnt2++] = mw * 32 + bit;
                }
            }
            for (int j = 0; j < KK; ++j) {
                int uu;
                if (j < ncv) {
                    uu = sorted_u[j];
                } else {
                    int idx = j - ncv;
                    if (idx > KK - 1) idx = KK - 1;
                    uu = cs[(size_t)i * KK + idx];
                }
                out[(size_t)i * KK + j] = uu;
            }
        }
    }
}

extern "C" void kernel_launch(void* const* d_in, const int* in_sizes, int n_in,
                              void* d_out, int out_size, void* d_ws, size_t ws_size,
                              hipStream_t stream)
{
    const float* x   = (const float*)d_in[0];
    const float* adj = (const float*)d_in[1];
    const int*   cs  = (const int*)d_in[2];
    int* out = (int*)d_out;

    fused_kernel<<<NN, NT, 0, stream>>>(
        x, reinterpret_cast<const uvec4*>(adj), cs, out);
}